// Round 2
// 753.530 us; speedup vs baseline: 1.0165x; 1.0165x over previous
//
#include <hip/hip_runtime.h>
#include <math.h>

// ---------------- degree via LDS-privatized multi-pass histogram ----------------
// dv (N floats) doesn't fit in LDS; split node range into P partitions of HB bins.
// Each partition is processed by BPP blocks, each streaming a contiguous edge chunk
// and accumulating in-range weights into LDS (cheap ds_add_f32 atomics). Partials
// are written with PLAIN coalesced stores (no global atomics -> no 32B write-through
// per edge, which is what made k_deg_accum cost 164us for a 400KB output).
#define HB  16384   // bins per partition = 64KB LDS
#define BPP 64      // blocks per partition

__global__ __launch_bounds__(256) void k_deg_hist(const int* __restrict__ col,
                                                  const float* __restrict__ w,
                                                  float* __restrict__ partial, int E) {
    __shared__ float bins[HB];
    int base = blockIdx.y * HB;
    for (int i = threadIdx.x; i < HB; i += 256) bins[i] = 0.f;
    __syncthreads();

    int chunk = (E + BPP - 1) / BPP;
    int e0 = blockIdx.x * chunk;
    int e1 = min(E, e0 + chunk);
    for (int e = e0 + threadIdx.x; e < e1; e += 256) {
        int c = col[e] - base;
        if ((unsigned)c < (unsigned)HB) atomicAdd(&bins[c], w[e]);
    }
    __syncthreads();

    float* out = partial + ((size_t)blockIdx.y * BPP + blockIdx.x) * HB;
    for (int i = threadIdx.x; i < HB; i += 256) out[i] = bins[i];
}

// dv[n] = rsqrt(1 + sum_b partial[part(n)][b][bin(n)])  -- fuses set_deg + dinv
__global__ void k_deg_reduce(const float* __restrict__ partial,
                             float* __restrict__ dv, int N) {
    int n = blockIdx.x * blockDim.x + threadIdx.x;
    if (n >= N) return;
    int part = n >> 14;            // n / HB
    int bin  = n & (HB - 1);
    const float* p = partial + ((size_t)part * BPP) * HB + bin;
    float s = 1.0f;                // self-loop weight
#pragma unroll 16
    for (int b = 0; b < BPP; b++) s += p[(size_t)b * HB];
    dv[n] = rsqrtf(s);
}

// ---------------- norm ----------------
__global__ void k_norm(const int* __restrict__ row, const int* __restrict__ col,
                       const float* __restrict__ w, const float* __restrict__ dv,
                       float* __restrict__ nrm, int E) {
    int e = blockIdx.x * blockDim.x + threadIdx.x;
    if (e < E) nrm[e] = dv[row[e]] * w[e] * dv[col[e]];
}

// ---------------- x @ W1  (N x 256 @ 256 x 16) ----------------
__global__ __launch_bounds__(256) void k_xw1(const float* __restrict__ x,
                                             const float* __restrict__ W1,
                                             float* __restrict__ h, int N) {
    __shared__ float xs[16][257];          // +1 pad: banks (r+k)%32 distinct
    __shared__ float wsh[256 * 16];
    int t = threadIdx.x;
    int base = blockIdx.x * 16;

    const float4* w4 = (const float4*)W1;
    float4* wsh4 = (float4*)wsh;
#pragma unroll
    for (int i = 0; i < 4; i++) wsh4[t + i * 256] = w4[t + i * 256];

    const float4* x4 = (const float4*)x;
    long xbase4 = (long)base * 64;
#pragma unroll
    for (int i = 0; i < 4; i++) {
        int p4 = t + i * 256;              // 0..1023 float4s = 16 rows x 64
        int r = p4 >> 6;
        int k = (p4 & 63) * 4;
        if (base + r < N) {
            float4 v = x4[xbase4 + p4];
            xs[r][k] = v.x; xs[r][k + 1] = v.y; xs[r][k + 2] = v.z; xs[r][k + 3] = v.w;
        }
    }
    __syncthreads();

    int r = t >> 4, j = t & 15;
    if (base + r < N) {
        float acc = 0.f;
#pragma unroll
        for (int k = 0; k < 256; k++) acc += xs[r][k] * wsh[k * 16 + j];
        h[(long)(base + r) * 16 + j] = acc;
    }
}

// ---------------- self-loop init: agg = dinv^2 * h ----------------
__global__ void k_agg_init(const float* __restrict__ h, const float* __restrict__ dv,
                           float* __restrict__ agg, int N16) {
    int i = blockIdx.x * blockDim.x + threadIdx.x;
    if (i < N16) {
        float d = dv[i >> 4];
        agg[i] = d * d * h[i];
    }
}

// ---------------- edge scatter: agg[col] += norm * h[row], 16 feats ----------------
__global__ void k_scatter(const int* __restrict__ row, const int* __restrict__ col,
                          const float* __restrict__ nrm, const float* __restrict__ h,
                          float* agg, int E) {
    int idx = blockIdx.x * blockDim.x + threadIdx.x;
    int e = idx >> 4, j = idx & 15;
    if (e < E) {
        int r = row[e], c = col[e];
        float v = nrm[e] * h[r * 16 + j];
        atomicAdd(&agg[c * 16 + j], v);
    }
}

// ---------------- h1 = relu(agg1 + b1) ----------------
__global__ void k_relu_bias(const float* __restrict__ agg, const float* __restrict__ b1,
                            float* __restrict__ h, int N16) {
    int i = blockIdx.x * blockDim.x + threadIdx.x;
    if (i < N16) h[i] = fmaxf(agg[i] + b1[i & 15], 0.f);
}

// ---------------- out = log_softmax(agg2 @ W2 + b2), wave per row ----------------
__global__ __launch_bounds__(256) void k_out(const float* __restrict__ agg2,
                                             const float* __restrict__ W2,
                                             const float* __restrict__ b2,
                                             float* __restrict__ out, int N) {
    int lane = threadIdx.x & 63;
    int wave = threadIdx.x >> 6;
    int rowi = blockIdx.x * 4 + wave;
    if (rowi >= N) return;

    float a[16];
#pragma unroll
    for (int j = 0; j < 16; j++) a[j] = agg2[(long)rowi * 16 + j];

    float acc = -INFINITY;
    if (lane < 40) {
        acc = b2[lane];
#pragma unroll
        for (int j = 0; j < 16; j++) acc += a[j] * W2[j * 40 + lane];
    }
    float m = acc;
#pragma unroll
    for (int off = 32; off; off >>= 1) m = fmaxf(m, __shfl_xor(m, off));
    float ex = (lane < 40) ? expf(acc - m) : 0.f;
    float s = ex;
#pragma unroll
    for (int off = 32; off; off >>= 1) s += __shfl_xor(s, off);
    if (lane < 40) out[(long)rowi * 40 + lane] = acc - m - logf(s);
}

extern "C" void kernel_launch(void* const* d_in, const int* in_sizes, int n_in,
                              void* d_out, int out_size, void* d_ws, size_t ws_size,
                              hipStream_t stream) {
    const float* x  = (const float*)d_in[0];
    const int*   ei = (const int*)d_in[1];
    const float* ew = (const float*)d_in[2];
    const float* W1 = (const float*)d_in[3];
    const float* b1 = (const float*)d_in[4];
    const float* W2 = (const float*)d_in[5];
    const float* b2 = (const float*)d_in[6];
    float* out = (float*)d_out;

    int N = in_sizes[0] / 256;
    int E = in_sizes[2];
    const int* row = ei;
    const int* col = ei + E;

    float* ws = (float*)d_ws;
    float* dv   = ws;                      // N
    float* nrm  = dv + N;                  // E
    float* h1   = nrm + E;                 // N*16 (xW1, later relu'd h1)
    float* agg1 = h1 + (size_t)N * 16;     // N*16
    float* agg2 = agg1 + (size_t)N * 16;   // N*16

    // deg-histogram partials (P*BPP*HB floats ~= 29.4MB) reuse the nrm/h1/agg
    // region: it is fully consumed by k_deg_reduce before k_norm writes nrm.
    float* partial = dv + N;

    const int B = 256;
    long e16 = (long)E * 16;
    int P = (N + HB - 1) / HB;             // 7 partitions for N=100000

    k_deg_hist  <<<dim3(BPP, P), 256, 0, stream>>>(col, ew, partial, E);
    k_deg_reduce<<<(N + B - 1) / B, B, 0, stream>>>(partial, dv, N);
    k_norm      <<<(E + B - 1) / B, B, 0, stream>>>(row, col, ew, dv, nrm, E);

    k_xw1       <<<(N + 15) / 16, 256, 0, stream>>>(x, W1, h1, N);

    k_agg_init  <<<(N * 16 + B - 1) / B, B, 0, stream>>>(h1, dv, agg1, N * 16);
    k_scatter   <<<(int)((e16 + B - 1) / B), B, 0, stream>>>(row, col, nrm, h1, agg1, E);
    k_relu_bias <<<(N * 16 + B - 1) / B, B, 0, stream>>>(agg1, b1, h1, N * 16);

    k_agg_init  <<<(N * 16 + B - 1) / B, B, 0, stream>>>(h1, dv, agg2, N * 16);
    k_scatter   <<<(int)((e16 + B - 1) / B), B, 0, stream>>>(row, col, nrm, h1, agg2, E);

    k_out       <<<(N + 3) / 4, 256, 0, stream>>>(agg2, W2, b2, out, N);
}